// Round 16
// baseline (337.703 us; speedup 1.0000x reference)
//
#include <hip/hip_runtime.h>
#include <hip/hip_bf16.h>
#include <stdint.h>

#define NN     30000
#define MPAD   30080          // 470 * 64 = 235 * 128
#define RR     8
#define NBASES 30
#define KD     256            // K of both GEMMs (in-dim of each layer)
#define EE     480000
#define NSEG   (NN * RR)
#define BK     64             // K-step; 8 chunks of 8 bf16 per row
#define CAP    32             // fixed segment capacity (Poisson(2): P(>32)~1e-20)
#define NC1    2304           // Y1 cols: 8*256 rel + 256 self
#define NC2    1152           // Y2 cols: 8*128 rel + 128 self

typedef unsigned short u16;
typedef __attribute__((ext_vector_type(8))) short bf16x8;   // 8 bf16 = 4 VGPRs
typedef __attribute__((ext_vector_type(4))) float f32x4;
typedef __attribute__((ext_vector_type(4))) unsigned int u32x4;  // NT-store-able

__device__ __forceinline__ u16 f2b(float f) {
  union { float f; uint32_t u; } v; v.f = f;
  return (u16)((v.u + 0x7fffu + ((v.u >> 16) & 1u)) >> 16);   // RNE
}
__device__ __forceinline__ float b2f(u16 h) {
  union { uint32_t u; float f; } v; v.u = ((uint32_t)h) << 16;
  return v.f;
}

__device__ __forceinline__ void gl_lds16(const void* g, void* l) {
  __builtin_amdgcn_global_load_lds((__attribute__((address_space(1))) void*)g,
                                   (__attribute__((address_space(3))) void*)l,
                                   16, 0, 0);
}

template<int N>
__device__ __forceinline__ void waitcnt_vm() {
  asm volatile("s_waitcnt vmcnt(%0)" :: "n"(N) : "memory");
}

// ------- dense transform GEMM: Y[M x NCOLS] = A[M x 256] @ Bn^T ------------
// r15 (second submission; r15 bench was an infra failure, never ran):
// r8/r11-measured config (BK=64, vmcnt(4), 2-barrier; 57.5-59us, 3.47 TB/s,
// 0 conflicts).  r12's BK=32 regressed (61.3us) -- reverted.
// ONLY change vs r8: the two 16B epilogue stores are nontemporal (cache-
// policy hint at the same dwordx4 width -- Y has zero reuse before its
// HBM-level re-read in k_agg, so skip L2/L3 write-allocate).  NT store uses
// clang ext_vector u32x4 (HIP's uint4 class is rejected by the builtin).
template<int NCOLS>
__global__ __launch_bounds__(512, 2)
void k_gemm_y(const u16* __restrict__ A, const u16* __restrict__ Bn,
              u16* __restrict__ Y) {
  constexpr int NT = 128, MT = 128;
  constexpr int MI = 2, NI = 4;         // wave tile 32 x 64
  constexpr int NKI = KD / BK;          // 4
  __shared__ __align__(16) char smem[65536];
  u16 (*Alds)[MT * BK] = (u16(*)[MT * BK])smem;                    // 2 x 16KB
  u16 (*Blds)[NT * BK] = (u16(*)[NT * BK])(smem + 2 * MT * BK * 2);// 2 x 16KB
  float* eps = (float*)smem;            // epilogue f32 tile [64][132]
  const int tid = threadIdx.x;          // 512 threads = 8 waves
  const int w = tid >> 6, lane = tid & 63;
  const int bn = blockIdx.x * NT, bm = blockIdx.y * MT;
  const int wm = (w >> 1) * 32;         // 4 m-wave-groups x 32 rows
  const int wn = (w & 1) * 64;          // 2 n-waves
  const int l15 = lane & 15, l4 = lane >> 4;

  f32x4 acc[MI][NI];
  #pragma unroll
  for (int mi = 0; mi < MI; ++mi)
    #pragma unroll
    for (int ni = 0; ni < NI; ++ni) acc[mi][ni] = (f32x4){0.f, 0.f, 0.f, 0.f};

  auto stage = [&](int buf, int k0) {   // 4 gl_lds16 per thread per tile
    // A tile: 128 rows x 8 chunks = 1024 chunks of 16B, 2 per thread
    #pragma unroll
    for (int it = 0; it < 2; ++it) {
      int chb = it * 512 + w * 64;       // wave-uniform dest base
      int ch = chb + lane;
      int row = ch >> 3, pc = ch & 7;
      int lc = pc ^ (row & 7);
      gl_lds16(&A[(size_t)(bm + row) * KD + k0 + lc * 8], &Alds[buf][chb * 8]);
    }
    // B tile: 128 rows x 8 chunks = 1024 chunks, 2 per thread
    #pragma unroll
    for (int it = 0; it < 2; ++it) {
      int chb = it * 512 + w * 64;
      int ch = chb + lane;
      int row = ch >> 3, pc = ch & 7;
      int lc = pc ^ (row & 7);
      gl_lds16(&Bn[(size_t)(bn + row) * KD + k0 + lc * 8], &Blds[buf][chb * 8]);
    }
  };

  stage(0, 0);                          // tile 0 in flight (4 loads)
  int buf = 0;
  for (int t = 0; t < NKI; ++t) {
    if (t + 1 < NKI) {
      stage(buf ^ 1, (t + 1) * BK);     // tile t+1 in flight (outstanding 8)
      waitcnt_vm<4>();                  // tile t landed; t+1 stays in flight
    } else {
      waitcnt_vm<0>();                  // last tile: full drain
    }
    __builtin_amdgcn_s_barrier();       // all waves' tile-t loads visible
    __builtin_amdgcn_sched_barrier(0);  // no LDS-read hoisting above barrier
    #pragma unroll
    for (int s = 0; s < 2; ++s) {        // two 32-K steps
      bf16x8 av[MI], bv[NI];
      #pragma unroll
      for (int mi = 0; mi < MI; ++mi) {
        int row = wm + mi * 16 + l15;
        int pc = (4 * s + l4) ^ (row & 7);
        av[mi] = *(const bf16x8*)&Alds[buf][row * BK + pc * 8];
      }
      #pragma unroll
      for (int ni = 0; ni < NI; ++ni) {
        int row = wn + ni * 16 + l15;
        int pc = (4 * s + l4) ^ (row & 7);
        bv[ni] = *(const bf16x8*)&Blds[buf][row * BK + pc * 8];
      }
      #pragma unroll
      for (int mi = 0; mi < MI; ++mi)
        #pragma unroll
        for (int ni = 0; ni < NI; ++ni)
          acc[mi][ni] = __builtin_amdgcn_mfma_f32_16x16x32_bf16(av[mi], bv[ni], acc[mi][ni], 0, 0, 0);
    }
    asm volatile("s_waitcnt lgkmcnt(0)" ::: "memory");  // reads of buf done
    __builtin_amdgcn_s_barrier();       // protect buf from next iter's stage
    buf ^= 1;
  }

  // epilogue via LDS, two 64-row passes (eps aliases staging buffers; the
  // loop's final barrier precedes first write).
  #pragma unroll
  for (int p = 0; p < 2; ++p) {
    if ((wm >> 6) == p) {
      #pragma unroll
      for (int mi = 0; mi < MI; ++mi)
        #pragma unroll
        for (int ni = 0; ni < NI; ++ni) {
          int col = wn + ni * 16 + l15;
          #pragma unroll
          for (int v = 0; v < 4; ++v) {
            int row = (wm & 63) + mi * 16 + l4 * 4 + v;
            eps[row * 132 + col] = acc[mi][ni][v];
          }
        }
    }
    __syncthreads();
    {
      int row = tid >> 3, oc = tid & 7;  // 64 rows x 8 col-octets (16 cols each)
      const float* src = &eps[row * 132 + oc * 16];
      u32x4 o[2];
      #pragma unroll
      for (int hh = 0; hh < 2; ++hh) {
        float f0 = src[hh*8+0], f1 = src[hh*8+1], f2 = src[hh*8+2], f3 = src[hh*8+3];
        float f4 = src[hh*8+4], f5 = src[hh*8+5], f6 = src[hh*8+6], f7 = src[hh*8+7];
        o[hh][0] = ((uint32_t)f2b(f1) << 16) | (uint32_t)f2b(f0);
        o[hh][1] = ((uint32_t)f2b(f3) << 16) | (uint32_t)f2b(f2);
        o[hh][2] = ((uint32_t)f2b(f5) << 16) | (uint32_t)f2b(f4);
        o[hh][3] = ((uint32_t)f2b(f7) << 16) | (uint32_t)f2b(f6);
      }
      u16* dst = &Y[(size_t)(bm + p * 64 + row) * NCOLS + bn + oc * 16];
      __builtin_nontemporal_store(o[0], (u32x4*)dst);
      __builtin_nontemporal_store(o[1], (u32x4*)(dst + 8));
    }
    __syncthreads();
  }
}

// ------- aggregate: out[d] = sum_r inv_r * sum_e Y[src_e, r-blk] + self + bias
// r6 structure kept: one HALFWAVE owns one dst end-to-end; no LDS/barriers.
template<int D, bool LAST>
__global__ __launch_bounds__(256)
void k_agg(const u16* __restrict__ Y, const int* __restrict__ cnt,
           const int* __restrict__ esrc, const float* __restrict__ bias,
           u16* __restrict__ ob, float* __restrict__ of) {
  constexpr int YW = 9 * D;             // Y row width
  constexpr int CW = D / 32;            // cols per lane (8 or 4)
  const int tid = threadIdx.x;
  const int h = tid >> 5, ln = tid & 31;
  const int d = blockIdx.x * 8 + h;     // grid 3750 x 8 = 30000 exact

  int cn[8];
  {
    int4 c0 = *(const int4*)&cnt[d << 3];
    int4 c1 = *(const int4*)&cnt[(d << 3) + 4];
    cn[0]=c0.x; cn[1]=c0.y; cn[2]=c0.z; cn[3]=c0.w;
    cn[4]=c1.x; cn[5]=c1.y; cn[6]=c1.z; cn[7]=c1.w;
  }
  int4 q[8];
  #pragma unroll
  for (int r = 0; r < 8; ++r)
    q[r] = *(const int4*)&esrc[((d << 3) + r) * CAP];

  float a[CW];
  #pragma unroll
  for (int j = 0; j < CW; ++j) a[j] = 0.f;

  #pragma unroll
  for (int r = 0; r < 8; ++r) {
    int n = cn[r] < CAP ? cn[r] : CAP;
    if (n == 0) continue;
    float t[CW];
    #pragma unroll
    for (int j = 0; j < CW; ++j) t[j] = 0.f;
    const int qsrc[4] = {q[r].x, q[r].y, q[r].z, q[r].w};
    #pragma unroll
    for (int e = 0; e < 4; ++e) {
      if (e < n) {
        int sr = qsrc[e];
        if constexpr (CW == 8) {
          uint4 v = *(const uint4*)&Y[(size_t)sr * YW + r * D + ln * 8];
          t[0]+=b2f((u16)v.x); t[1]+=b2f((u16)(v.x>>16));
          t[2]+=b2f((u16)v.y); t[3]+=b2f((u16)(v.y>>16));
          t[4]+=b2f((u16)v.z); t[5]+=b2f((u16)(v.z>>16));
          t[6]+=b2f((u16)v.w); t[7]+=b2f((u16)(v.w>>16));
        } else {
          uint2 v = *(const uint2*)&Y[(size_t)sr * YW + r * D + ln * 4];
          t[0]+=b2f((u16)v.x); t[1]+=b2f((u16)(v.x>>16));
          t[2]+=b2f((u16)v.y); t[3]+=b2f((u16)(v.y>>16));
        }
      }
    }
    #pragma unroll 1
    for (int e = 4; e < n; ++e) {
      int sr = esrc[((d << 3) + r) * CAP + e];
      if constexpr (CW == 8) {
        uint4 v = *(const uint4*)&Y[(size_t)sr * YW + r * D + ln * 8];
        t[0]+=b2f((u16)v.x); t[1]+=b2f((u16)(v.x>>16));
        t[2]+=b2f((u16)v.y); t[3]+=b2f((u16)(v.y>>16));
        t[4]+=b2f((u16)v.z); t[5]+=b2f((u16)(v.z>>16));
        t[6]+=b2f((u16)v.w); t[7]+=b2f((u16)(v.w>>16));
      } else {
        uint2 v = *(const uint2*)&Y[(size_t)sr * YW + r * D + ln * 4];
        t[0]+=b2f((u16)v.x); t[1]+=b2f((u16)(v.x>>16));
        t[2]+=b2f((u16)v.y); t[3]+=b2f((u16)(v.y>>16));
      }
    }
    float inv = 1.f / (float)n;
    #pragma unroll
    for (int j = 0; j < CW; ++j) a[j] = fmaf(inv, t[j], a[j]);
  }

  // self term + bias + activation + store (halfwave-local, no reduce)
  if constexpr (CW == 8) {
    uint4 sv = *(const uint4*)&Y[(size_t)d * YW + 8 * D + ln * 8];
    float s[8] = { b2f((u16)sv.x), b2f((u16)(sv.x>>16)),
                   b2f((u16)sv.y), b2f((u16)(sv.y>>16)),
                   b2f((u16)sv.z), b2f((u16)(sv.z>>16)),
                   b2f((u16)sv.w), b2f((u16)(sv.w>>16)) };
    float4 b0 = *(const float4*)&bias[ln * 8];
    float4 b1 = *(const float4*)&bias[ln * 8 + 4];
    float vv[8];
    vv[0]=a[0]+s[0]+b0.x; vv[1]=a[1]+s[1]+b0.y;
    vv[2]=a[2]+s[2]+b0.z; vv[3]=a[3]+s[3]+b0.w;
    vv[4]=a[4]+s[4]+b1.x; vv[5]=a[5]+s[5]+b1.y;
    vv[6]=a[6]+s[6]+b1.z; vv[7]=a[7]+s[7]+b1.w;
    if (!LAST) {
      #pragma unroll
      for (int j = 0; j < 8; ++j) vv[j] = vv[j] > 0.f ? vv[j] : 0.01f * vv[j];
      uint4 o;
      o.x = ((uint32_t)f2b(vv[1]) << 16) | (uint32_t)f2b(vv[0]);
      o.y = ((uint32_t)f2b(vv[3]) << 16) | (uint32_t)f2b(vv[2]);
      o.z = ((uint32_t)f2b(vv[5]) << 16) | (uint32_t)f2b(vv[4]);
      o.w = ((uint32_t)f2b(vv[7]) << 16) | (uint32_t)f2b(vv[6]);
      *(uint4*)&ob[(size_t)d * KD + ln * 8] = o;
    } else {
      float4 o0 = {vv[0], vv[1], vv[2], vv[3]};
      float4 o1 = {vv[4], vv[5], vv[6], vv[7]};
      *(float4*)&of[(size_t)d * 256 + ln * 8] = o0;
      *(float4*)&of[(size_t)d * 256 + ln * 8 + 4] = o1;
    }
  } else {
    uint2 sv = *(const uint2*)&Y[(size_t)d * YW + 8 * D + ln * 4];
    float s[4] = { b2f((u16)sv.x), b2f((u16)(sv.x>>16)),
                   b2f((u16)sv.y), b2f((u16)(sv.y>>16)) };
    float4 b0 = *(const float4*)&bias[ln * 4];
    float vv[4];
    vv[0]=a[0]+s[0]+b0.x; vv[1]=a[1]+s[1]+b0.y;
    vv[2]=a[2]+s[2]+b0.z; vv[3]=a[3]+s[3]+b0.w;
    if (!LAST) {
      #pragma unroll
      for (int j = 0; j < 4; ++j) vv[j] = vv[j] > 0.f ? vv[j] : 0.01f * vv[j];
      uint2 o;
      o.x = ((uint32_t)f2b(vv[1]) << 16) | (uint32_t)f2b(vv[0]);
      o.y = ((uint32_t)f2b(vv[3]) << 16) | (uint32_t)f2b(vv[2]);
      *(uint2*)&ob[(size_t)d * KD + ln * 4] = o;
    } else {
      float4 o = {vv[0], vv[1], vv[2], vv[3]};
      *(float4*)&of[(size_t)d * 128 + ln * 4] = o;
    }
  }
}

// ------- fused prologue: cast_x | combineT1 | combineT2 | bucket -----------
// Replaces 4 serialized small launches with ONE kernel (block-range
// dispatch).  Bodies bitwise-identical to the previous separate kernels;
// only the thread->work mapping of combineT2 changed (2 i's per 256-thr
// block instead of 128-thr blocks) -- same values written.
#define PB_CAST   7500                  // 30000*256/4/256
#define PB_CT1    2304                  // 256 i x 9 rg
#define PB_CT2    1152                  // 9 rg x 128 i-pairs
#define PB_BKT    1875                  // ceil(480000/256)
#define PB_TOT    (PB_CAST + PB_CT1 + PB_CT2 + PB_BKT)

__global__ __launch_bounds__(256)
void k_prep(const float* __restrict__ x, u16* __restrict__ xb,
            const float* __restrict__ bases1, const float* __restrict__ comp1,
            const float* __restrict__ root1, u16* __restrict__ Bn1,
            const float* __restrict__ bases2, const float* __restrict__ comp2,
            const float* __restrict__ root2, u16* __restrict__ Bn2,
            const int* __restrict__ ei, const int* __restrict__ ety,
            int* __restrict__ cnt, int* __restrict__ esrc) {
  const int b = blockIdx.x, tid = threadIdx.x;
  if (b < PB_CAST) {
    // cast x f32 -> bf16
    int t = b * 256 + tid;
    if (t < NN * KD / 4) {
      float4 v = ((const float4*)x)[t];
      union { u16 h[4]; uint2 u; } p;
      p.h[0] = f2b(v.x); p.h[1] = f2b(v.y); p.h[2] = f2b(v.z); p.h[3] = f2b(v.w);
      ((uint2*)xb)[t] = p.u;
    }
  } else if (b < PB_CAST + PB_CT1) {
    // Bn1[j*256+k]: j=rg*256+o (rg<8) else 2048+o
    int cb = b - PB_CAST;
    int i = cb & 255, rg = cb >> 8, o = tid;
    float v; int j;
    if (rg < RR) {
      float acc = 0.f;
      #pragma unroll
      for (int bb = 0; bb < NBASES; ++bb)
        acc += comp1[rg * NBASES + bb] * bases1[(size_t)bb * 65536 + i * 256 + o];
      v = acc; j = rg * 256 + o;
    } else {
      v = root1[i * 256 + o]; j = 2048 + o;
    }
    Bn1[(size_t)j * KD + i] = f2b(v);
  } else if (b < PB_CAST + PB_CT1 + PB_CT2) {
    // Bn2: two i's per block (tid>>7 selects), o = tid&127
    int cb = b - PB_CAST - PB_CT1;
    int rg = cb >> 7, ipair = cb & 127;
    int i = ipair * 2 + (tid >> 7), o = tid & 127;
    float v; int j;
    if (rg < RR) {
      float acc = 0.f;
      #pragma unroll
      for (int bb = 0; bb < NBASES; ++bb)
        acc += comp2[rg * NBASES + bb] * bases2[(size_t)bb * 32768 + i * 128 + o];
      v = acc; j = rg * 128 + o;
    } else {
      v = root2[i * 128 + o]; j = 1024 + o;
    }
    Bn2[(size_t)j * KD + i] = f2b(v);
  } else {
    // fixed-stride bucket
    int e = (b - PB_CAST - PB_CT1 - PB_CT2) * 256 + tid;
    if (e < EE) {
      int seg = ei[EE + e] * RR + ety[e];
      int pos = atomicAdd(&cnt[seg], 1);
      if (pos < CAP) esrc[seg * CAP + pos] = ei[e];
    }
  }
}

// ------- launch -------------------------------------------------------------
extern "C" void kernel_launch(void* const* d_in, const int* in_sizes, int n_in,
                              void* d_out, int out_size, void* d_ws, size_t ws_size,
                              hipStream_t stream) {
  const float* x      = (const float*)d_in[0];
  const int*   ei     = (const int*)d_in[1];
  const int*   ety    = (const int*)d_in[2];
  const float* bases1 = (const float*)d_in[3];
  const float* comp1  = (const float*)d_in[4];
  const float* root1  = (const float*)d_in[5];
  const float* bias1  = (const float*)d_in[6];
  const float* bases2 = (const float*)d_in[7];
  const float* comp2  = (const float*)d_in[8];
  const float* root2  = (const float*)d_in[9];
  const float* bias2  = (const float*)d_in[10];
  float* out = (float*)d_out;

  char* p = (char*)d_ws;
  auto alloc = [&](size_t bytes) {
    char* q = p; p += (bytes + 255) & ~(size_t)255; return q;
  };
  u16* Y    = (u16*)alloc((size_t)MPAD * NC1 * 2);     // 138.6 MB, reused layer 2
  u16* xb   = (u16*)alloc((size_t)MPAD * KD * 2);
  u16* z1b  = (u16*)alloc((size_t)MPAD * KD * 2);
  u16* Bn1  = (u16*)alloc((size_t)NC1 * KD * 2);
  u16* Bn2  = (u16*)alloc((size_t)NC2 * KD * 2);
  int* cnt  = (int*)alloc((size_t)NSEG * 4);
  int* esrc = (int*)alloc((size_t)NSEG * CAP * 4);     // 30.7 MB fixed-stride

  // prologue: memset + ONE fused kernel (cast | combine1 | combine2 | bucket)
  hipMemsetAsync(cnt, 0, (size_t)NSEG * 4, stream);
  k_prep<<<PB_TOT, 256, 0, stream>>>(x, xb, bases1, comp1, root1, Bn1,
                                     bases2, comp2, root2, Bn2,
                                     ei, ety, cnt, esrc);

  // layer 1: Y = xb @ Bn1^T; z1b = leaky(agg(Y) + bias1)
  k_gemm_y<NC1><<<dim3(NC1 / 128, MPAD / 128), 512, 0, stream>>>(xb, Bn1, Y);
  k_agg<256, false><<<NN / 8, 256, 0, stream>>>(Y, cnt, esrc, bias1, z1b, nullptr);

  // layer 2: Y = z1b @ Bn2^T; out = agg(Y) + bias2
  k_gemm_y<NC2><<<dim3(NC2 / 128, MPAD / 128), 512, 0, stream>>>(z1b, Bn2, Y);
  k_agg<128, true><<<NN / 8, 256, 0, stream>>>(Y, cnt, esrc, bias2, nullptr, out);
}

// Round 18
// 321.265 us; speedup vs baseline: 1.0512x; 1.0512x over previous
//
#include <hip/hip_runtime.h>
#include <hip/hip_bf16.h>
#include <stdint.h>

#define NN     30000
#define MPAD   30080          // 470 * 64 = 235 * 128
#define RR     8
#define NBASES 30
#define KD     256            // K of both GEMMs (in-dim of each layer)
#define EE     480000
#define NSEG   (NN * RR)
#define BK     64             // K-step; 8 chunks of 8 bf16 per row
#define CAP    32             // fixed segment capacity (Poisson(2): P(>32)~1e-20)
#define NC1    2304           // Y1 cols: 8*256 rel + 256 self
#define NC2    1152           // Y2 cols: 8*128 rel + 128 self

typedef unsigned short u16;
typedef __attribute__((ext_vector_type(8))) short bf16x8;   // 8 bf16 = 4 VGPRs
typedef __attribute__((ext_vector_type(4))) float f32x4;

__device__ __forceinline__ u16 f2b(float f) {
  union { float f; uint32_t u; } v; v.f = f;
  return (u16)((v.u + 0x7fffu + ((v.u >> 16) & 1u)) >> 16);   // RNE
}
__device__ __forceinline__ float b2f(u16 h) {
  union { uint32_t u; float f; } v; v.u = ((uint32_t)h) << 16;
  return v.f;
}

__device__ __forceinline__ void gl_lds16(const void* g, void* l) {
  __builtin_amdgcn_global_load_lds((__attribute__((address_space(1))) void*)g,
                                   (__attribute__((address_space(3))) void*)l,
                                   16, 0, 0);
}

template<int N>
__device__ __forceinline__ void waitcnt_vm() {
  asm volatile("s_waitcnt vmcnt(%0)" :: "n"(N) : "memory");
}

// ------- dense transform GEMM: Y[M x NCOLS] = A[M x 256] @ Bn^T ------------
// r17 (second submission; r17 bench was an infra failure, never ran):
// r11-exact GEMM (BK=64, counted vmcnt(4), 2-barrier; measured 58.5us,
// 3.47 TB/s, 0 conflicts).  r16's NT-store + prep-fusion bundle regressed
// +10us total (unattributable) -- both reverted.
template<int NCOLS>
__global__ __launch_bounds__(512, 2)
void k_gemm_y(const u16* __restrict__ A, const u16* __restrict__ Bn,
              u16* __restrict__ Y) {
  constexpr int NT = 128, MT = 128;
  constexpr int MI = 2, NI = 4;         // wave tile 32 x 64
  constexpr int NKI = KD / BK;          // 4
  __shared__ __align__(16) char smem[65536];
  u16 (*Alds)[MT * BK] = (u16(*)[MT * BK])smem;                    // 2 x 16KB
  u16 (*Blds)[NT * BK] = (u16(*)[NT * BK])(smem + 2 * MT * BK * 2);// 2 x 16KB
  float* eps = (float*)smem;            // epilogue f32 tile [64][132]
  const int tid = threadIdx.x;          // 512 threads = 8 waves
  const int w = tid >> 6, lane = tid & 63;
  const int bn = blockIdx.x * NT, bm = blockIdx.y * MT;
  const int wm = (w >> 1) * 32;         // 4 m-wave-groups x 32 rows
  const int wn = (w & 1) * 64;          // 2 n-waves
  const int l15 = lane & 15, l4 = lane >> 4;

  f32x4 acc[MI][NI];
  #pragma unroll
  for (int mi = 0; mi < MI; ++mi)
    #pragma unroll
    for (int ni = 0; ni < NI; ++ni) acc[mi][ni] = (f32x4){0.f, 0.f, 0.f, 0.f};

  auto stage = [&](int buf, int k0) {   // 4 gl_lds16 per thread per tile
    #pragma unroll
    for (int it = 0; it < 2; ++it) {
      int chb = it * 512 + w * 64;       // wave-uniform dest base
      int ch = chb + lane;
      int row = ch >> 3, pc = ch & 7;
      int lc = pc ^ (row & 7);
      gl_lds16(&A[(size_t)(bm + row) * KD + k0 + lc * 8], &Alds[buf][chb * 8]);
    }
    #pragma unroll
    for (int it = 0; it < 2; ++it) {
      int chb = it * 512 + w * 64;
      int ch = chb + lane;
      int row = ch >> 3, pc = ch & 7;
      int lc = pc ^ (row & 7);
      gl_lds16(&Bn[(size_t)(bn + row) * KD + k0 + lc * 8], &Blds[buf][chb * 8]);
    }
  };

  stage(0, 0);                          // tile 0 in flight (4 loads)
  int buf = 0;
  for (int t = 0; t < NKI; ++t) {
    if (t + 1 < NKI) {
      stage(buf ^ 1, (t + 1) * BK);     // tile t+1 in flight (outstanding 8)
      waitcnt_vm<4>();                  // tile t landed; t+1 stays in flight
    } else {
      waitcnt_vm<0>();                  // last tile: full drain
    }
    __builtin_amdgcn_s_barrier();       // all waves' tile-t loads visible
    __builtin_amdgcn_sched_barrier(0);  // no LDS-read hoisting above barrier
    #pragma unroll
    for (int s = 0; s < 2; ++s) {        // two 32-K steps
      bf16x8 av[MI], bv[NI];
      #pragma unroll
      for (int mi = 0; mi < MI; ++mi) {
        int row = wm + mi * 16 + l15;
        int pc = (4 * s + l4) ^ (row & 7);
        av[mi] = *(const bf16x8*)&Alds[buf][row * BK + pc * 8];
      }
      #pragma unroll
      for (int ni = 0; ni < NI; ++ni) {
        int row = wn + ni * 16 + l15;
        int pc = (4 * s + l4) ^ (row & 7);
        bv[ni] = *(const bf16x8*)&Blds[buf][row * BK + pc * 8];
      }
      #pragma unroll
      for (int mi = 0; mi < MI; ++mi)
        #pragma unroll
        for (int ni = 0; ni < NI; ++ni)
          acc[mi][ni] = __builtin_amdgcn_mfma_f32_16x16x32_bf16(av[mi], bv[ni], acc[mi][ni], 0, 0, 0);
    }
    asm volatile("s_waitcnt lgkmcnt(0)" ::: "memory");  // reads of buf done
    __builtin_amdgcn_s_barrier();       // protect buf from next iter's stage
    buf ^= 1;
  }

  // epilogue via LDS, two 64-row passes
  #pragma unroll
  for (int p = 0; p < 2; ++p) {
    if ((wm >> 6) == p) {
      #pragma unroll
      for (int mi = 0; mi < MI; ++mi)
        #pragma unroll
        for (int ni = 0; ni < NI; ++ni) {
          int col = wn + ni * 16 + l15;
          #pragma unroll
          for (int v = 0; v < 4; ++v) {
            int row = (wm & 63) + mi * 16 + l4 * 4 + v;
            eps[row * 132 + col] = acc[mi][ni][v];
          }
        }
    }
    __syncthreads();
    {
      int row = tid >> 3, oc = tid & 7;  // 64 rows x 8 col-octets (16 cols each)
      const float* src = &eps[row * 132 + oc * 16];
      uint4 o[2];
      #pragma unroll
      for (int hh = 0; hh < 2; ++hh) {
        float f0 = src[hh*8+0], f1 = src[hh*8+1], f2 = src[hh*8+2], f3 = src[hh*8+3];
        float f4 = src[hh*8+4], f5 = src[hh*8+5], f6 = src[hh*8+6], f7 = src[hh*8+7];
        o[hh].x = ((uint32_t)f2b(f1) << 16) | (uint32_t)f2b(f0);
        o[hh].y = ((uint32_t)f2b(f3) << 16) | (uint32_t)f2b(f2);
        o[hh].z = ((uint32_t)f2b(f5) << 16) | (uint32_t)f2b(f4);
        o[hh].w = ((uint32_t)f2b(f7) << 16) | (uint32_t)f2b(f6);
      }
      u16* dst = &Y[(size_t)(bm + p * 64 + row) * NCOLS + bn + oc * 16];
      *(uint4*)dst = o[0];
      *(uint4*)(dst + 8) = o[1];
    }
    __syncthreads();
  }
}

// ------- aggregate: out[d] = sum_r inv_r * sum_e Y[src_e, r-blk] + self + bias
// r17: ILP fix.  r16 counters: 64.5us, 2.4 TB/s (30% peak), VGPR=36 -->
// the compiler serialized the gather chain (no registers to batch loads).
// Restructure: two REL-QUADS; per quad, issue ALL <=16 independent Y-row
// loads (4 rels x 4 prefetched edges) into named registers FIRST, then
// unpack/accumulate.  Guards are halfwave-uniform; indices static.
// Accumulation order bitwise-identical to the passing r16 kernel
// (per-rel t in e-order, serial tail e>=4, a=fma(inv,t,a) in r-order).
template<int D, bool LAST>
__global__ __launch_bounds__(256)
void k_agg(const u16* __restrict__ Y, const int* __restrict__ cnt,
           const int* __restrict__ esrc, const float* __restrict__ bias,
           u16* __restrict__ ob, float* __restrict__ of) {
  constexpr int YW = 9 * D;             // Y row width
  constexpr int CW = D / 32;            // cols per lane (8 or 4)
  const int tid = threadIdx.x;
  const int h = tid >> 5, ln = tid & 31;
  const int d = blockIdx.x * 8 + h;     // grid 3750 x 8 = 30000 exact

  int cn[8];
  {
    int4 c0 = *(const int4*)&cnt[d << 3];
    int4 c1 = *(const int4*)&cnt[(d << 3) + 4];
    cn[0]=c0.x; cn[1]=c0.y; cn[2]=c0.z; cn[3]=c0.w;
    cn[4]=c1.x; cn[5]=c1.y; cn[6]=c1.z; cn[7]=c1.w;
    #pragma unroll
    for (int r = 0; r < 8; ++r) cn[r] = cn[r] < CAP ? cn[r] : CAP;
  }
  int4 q[8];
  #pragma unroll
  for (int r = 0; r < 8; ++r)
    q[r] = *(const int4*)&esrc[((d << 3) + r) * CAP];

  float a[CW];
  #pragma unroll
  for (int j = 0; j < CW; ++j) a[j] = 0.f;

  #pragma unroll
  for (int qd = 0; qd < 2; ++qd) {
    // ---- batched load phase: 4 rels x up to 4 edges, all independent ----
    uint4 y4[4][4];
    uint2 y2[4][4];
    #pragma unroll
    for (int rr = 0; rr < 4; ++rr) {
      const int r = qd * 4 + rr;
      const int n = cn[r];
      const int qs[4] = {q[r].x, q[r].y, q[r].z, q[r].w};
      #pragma unroll
      for (int e = 0; e < 4; ++e) {
        if (e < n) {
          if constexpr (CW == 8)
            y4[rr][e] = *(const uint4*)&Y[(size_t)qs[e] * YW + r * D + ln * 8];
          else
            y2[rr][e] = *(const uint2*)&Y[(size_t)qs[e] * YW + r * D + ln * 4];
        }
      }
    }
    // ---- accumulate phase (order identical to previous kernel) ----
    #pragma unroll
    for (int rr = 0; rr < 4; ++rr) {
      const int r = qd * 4 + rr;
      const int n = cn[r];
      if (n == 0) continue;
      float t[CW];
      #pragma unroll
      for (int j = 0; j < CW; ++j) t[j] = 0.f;
      #pragma unroll
      for (int e = 0; e < 4; ++e) {
        if (e < n) {
          if constexpr (CW == 8) {
            uint4 v = y4[rr][e];
            t[0]+=b2f((u16)v.x); t[1]+=b2f((u16)(v.x>>16));
            t[2]+=b2f((u16)v.y); t[3]+=b2f((u16)(v.y>>16));
            t[4]+=b2f((u16)v.z); t[5]+=b2f((u16)(v.z>>16));
            t[6]+=b2f((u16)v.w); t[7]+=b2f((u16)(v.w>>16));
          } else {
            uint2 v = y2[rr][e];
            t[0]+=b2f((u16)v.x); t[1]+=b2f((u16)(v.x>>16));
            t[2]+=b2f((u16)v.y); t[3]+=b2f((u16)(v.y>>16));
          }
        }
      }
      #pragma unroll 1
      for (int e = 4; e < n; ++e) {
        int sr = esrc[((d << 3) + r) * CAP + e];
        if constexpr (CW == 8) {
          uint4 v = *(const uint4*)&Y[(size_t)sr * YW + r * D + ln * 8];
          t[0]+=b2f((u16)v.x); t[1]+=b2f((u16)(v.x>>16));
          t[2]+=b2f((u16)v.y); t[3]+=b2f((u16)(v.y>>16));
          t[4]+=b2f((u16)v.z); t[5]+=b2f((u16)(v.z>>16));
          t[6]+=b2f((u16)v.w); t[7]+=b2f((u16)(v.w>>16));
        } else {
          uint2 v = *(const uint2*)&Y[(size_t)sr * YW + r * D + ln * 4];
          t[0]+=b2f((u16)v.x); t[1]+=b2f((u16)(v.x>>16));
          t[2]+=b2f((u16)v.y); t[3]+=b2f((u16)(v.y>>16));
        }
      }
      float inv = 1.f / (float)n;
      #pragma unroll
      for (int j = 0; j < CW; ++j) a[j] = fmaf(inv, t[j], a[j]);
    }
  }

  // self term + bias + activation + store (halfwave-local, no reduce)
  if constexpr (CW == 8) {
    uint4 sv = *(const uint4*)&Y[(size_t)d * YW + 8 * D + ln * 8];
    float s[8] = { b2f((u16)sv.x), b2f((u16)(sv.x>>16)),
                   b2f((u16)sv.y), b2f((u16)(sv.y>>16)),
                   b2f((u16)sv.z), b2f((u16)(sv.z>>16)),
                   b2f((u16)sv.w), b2f((u16)(sv.w>>16)) };
    float4 b0 = *(const float4*)&bias[ln * 8];
    float4 b1 = *(const float4*)&bias[ln * 8 + 4];
    float vv[8];
    vv[0]=a[0]+s[0]+b0.x; vv[1]=a[1]+s[1]+b0.y;
    vv[2]=a[2]+s[2]+b0.z; vv[3]=a[3]+s[3]+b0.w;
    vv[4]=a[4]+s[4]+b1.x; vv[5]=a[5]+s[5]+b1.y;
    vv[6]=a[6]+s[6]+b1.z; vv[7]=a[7]+s[7]+b1.w;
    if (!LAST) {
      #pragma unroll
      for (int j = 0; j < 8; ++j) vv[j] = vv[j] > 0.f ? vv[j] : 0.01f * vv[j];
      uint4 o;
      o.x = ((uint32_t)f2b(vv[1]) << 16) | (uint32_t)f2b(vv[0]);
      o.y = ((uint32_t)f2b(vv[3]) << 16) | (uint32_t)f2b(vv[2]);
      o.z = ((uint32_t)f2b(vv[5]) << 16) | (uint32_t)f2b(vv[4]);
      o.w = ((uint32_t)f2b(vv[7]) << 16) | (uint32_t)f2b(vv[6]);
      *(uint4*)&ob[(size_t)d * KD + ln * 8] = o;
    } else {
      float4 o0 = {vv[0], vv[1], vv[2], vv[3]};
      float4 o1 = {vv[4], vv[5], vv[6], vv[7]};
      *(float4*)&of[(size_t)d * 256 + ln * 8] = o0;
      *(float4*)&of[(size_t)d * 256 + ln * 8 + 4] = o1;
    }
  } else {
    uint2 sv = *(const uint2*)&Y[(size_t)d * YW + 8 * D + ln * 4];
    float s[4] = { b2f((u16)sv.x), b2f((u16)(sv.x>>16)),
                   b2f((u16)sv.y), b2f((u16)(sv.y>>16)) };
    float4 b0 = *(const float4*)&bias[ln * 4];
    float vv[4];
    vv[0]=a[0]+s[0]+b0.x; vv[1]=a[1]+s[1]+b0.y;
    vv[2]=a[2]+s[2]+b0.z; vv[3]=a[3]+s[3]+b0.w;
    if (!LAST) {
      #pragma unroll
      for (int j = 0; j < 4; ++j) vv[j] = vv[j] > 0.f ? vv[j] : 0.01f * vv[j];
      uint2 o;
      o.x = ((uint32_t)f2b(vv[1]) << 16) | (uint32_t)f2b(vv[0]);
      o.y = ((uint32_t)f2b(vv[3]) << 16) | (uint32_t)f2b(vv[2]);
      *(uint2*)&ob[(size_t)d * KD + ln * 4] = o;
    } else {
      float4 o = {vv[0], vv[1], vv[2], vv[3]};
      *(float4*)&of[(size_t)d * 128 + ln * 4] = o;
    }
  }
}

// ------- small kernels (r11-exact) -----------------------------------------
__global__ void k_cast_x(const float* __restrict__ x, u16* __restrict__ xb) {
  int t = blockIdx.x * 256 + threadIdx.x;
  if (t < NN * KD / 4) {
    float4 v = ((const float4*)x)[t];
    union { u16 h[4]; uint2 u; } p;
    p.h[0] = f2b(v.x); p.h[1] = f2b(v.y); p.h[2] = f2b(v.z); p.h[3] = f2b(v.w);
    ((uint2*)xb)[t] = p.u;
  }
}

__global__ void k_combineT1(const float* __restrict__ bases, const float* __restrict__ comp,
                            const float* __restrict__ root, u16* __restrict__ Bn) {
  int i = blockIdx.x, rg = blockIdx.y, o = threadIdx.x;   // 256 x 9 x 256
  float v; int j;
  if (rg < RR) {
    float acc = 0.f;
    #pragma unroll
    for (int b = 0; b < NBASES; ++b)
      acc += comp[rg * NBASES + b] * bases[(size_t)b * 65536 + i * 256 + o];
    v = acc; j = rg * 256 + o;
  } else {
    v = root[i * 256 + o]; j = 2048 + o;
  }
  Bn[(size_t)j * KD + i] = f2b(v);
}

__global__ void k_combineT2(const float* __restrict__ bases, const float* __restrict__ comp,
                            const float* __restrict__ root, u16* __restrict__ Bn) {
  int i = blockIdx.x, rg = blockIdx.y, o = threadIdx.x;   // 256 x 9 x 128
  float v; int j;
  if (rg < RR) {
    float acc = 0.f;
    #pragma unroll
    for (int b = 0; b < NBASES; ++b)
      acc += comp[rg * NBASES + b] * bases[(size_t)b * 32768 + i * 128 + o];
    v = acc; j = rg * 128 + o;
  } else {
    v = root[i * 128 + o]; j = 1024 + o;
  }
  Bn[(size_t)j * KD + i] = f2b(v);
}

__global__ void k_bucket_fs(const int* __restrict__ ei, const int* __restrict__ ety,
                            int* __restrict__ cnt, int* __restrict__ esrc) {
  int e = blockIdx.x * 256 + threadIdx.x;
  if (e < EE) {
    int seg = ei[EE + e] * RR + ety[e];
    int pos = atomicAdd(&cnt[seg], 1);
    if (pos < CAP) esrc[seg * CAP + pos] = ei[e];
  }
}

// ------- launch -------------------------------------------------------------
extern "C" void kernel_launch(void* const* d_in, const int* in_sizes, int n_in,
                              void* d_out, int out_size, void* d_ws, size_t ws_size,
                              hipStream_t stream) {
  const float* x      = (const float*)d_in[0];
  const int*   ei     = (const int*)d_in[1];
  const int*   ety    = (const int*)d_in[2];
  const float* bases1 = (const float*)d_in[3];
  const float* comp1  = (const float*)d_in[4];
  const float* root1  = (const float*)d_in[5];
  const float* bias1  = (const float*)d_in[6];
  const float* bases2 = (const float*)d_in[7];
  const float* comp2  = (const float*)d_in[8];
  const float* root2  = (const float*)d_in[9];
  const float* bias2  = (const float*)d_in[10];
  float* out = (float*)d_out;

  char* p = (char*)d_ws;
  auto alloc = [&](size_t bytes) {
    char* q = p; p += (bytes + 255) & ~(size_t)255; return q;
  };
  u16* Y    = (u16*)alloc((size_t)MPAD * NC1 * 2);     // 138.6 MB, reused layer 2
  u16* xb   = (u16*)alloc((size_t)MPAD * KD * 2);
  u16* z1b  = (u16*)alloc((size_t)MPAD * KD * 2);
  u16* Bn1  = (u16*)alloc((size_t)NC1 * KD * 2);
  u16* Bn2  = (u16*)alloc((size_t)NC2 * KD * 2);
  int* cnt  = (int*)alloc((size_t)NSEG * 4);
  int* esrc = (int*)alloc((size_t)NSEG * CAP * 4);     // 30.7 MB fixed-stride

  // fixed-stride CSR (no scans)
  hipMemsetAsync(cnt, 0, (size_t)NSEG * 4, stream);
  k_bucket_fs<<<(EE + 255) / 256, 256, 0, stream>>>(ei, ety, cnt, esrc);

  // weights + input cast
  k_cast_x<<<NN * KD / 4 / 256, 256, 0, stream>>>(x, xb);
  k_combineT1<<<dim3(256, 9), 256, 0, stream>>>(bases1, comp1, root1, Bn1);
  k_combineT2<<<dim3(256, 9), 128, 0, stream>>>(bases2, comp2, root2, Bn2);

  // layer 1: Y = xb @ Bn1^T; z1b = leaky(agg(Y) + bias1)
  k_gemm_y<NC1><<<dim3(NC1 / 128, MPAD / 128), 512, 0, stream>>>(xb, Bn1, Y);
  k_agg<256, false><<<NN / 8, 256, 0, stream>>>(Y, cnt, esrc, bias1, z1b, nullptr);

  // layer 2: Y = z1b @ Bn2^T; out = agg(Y) + bias2
  k_gemm_y<NC2><<<dim3(NC2 / 128, MPAD / 128), 512, 0, stream>>>(z1b, Bn2, Y);
  k_agg<128, true><<<NN / 8, 256, 0, stream>>>(Y, cnt, esrc, bias2, nullptr, out);
}